// Round 5
// baseline (221.381 us; speedup 1.0000x reference)
//
#include <hip/hip_runtime.h>

#define N_NODES 2000
#define NP      2048    // Sp n-dim padding
#define KB      63      // ceil(2000/32) k-blocks (k padded to 2016 with zeros)
#define BATCH   32
#define DIM     64      // DIM_IN == DIM_OUT
#define EMB     16
#define KI      192     // CHEB_K * DIM_IN
#define WCOLS   12288   // DIM_OUT * KI

typedef __bf16 bf16;
typedef __attribute__((ext_vector_type(8))) __bf16 bf16x8;
typedef __attribute__((ext_vector_type(4))) float  f32x4;

struct alignas(8) bf16x4pk { bf16 v[4]; };

// ---------------------------------------------------------------------------
// Kernel 1: softmax(relu(nv1@nv2)) row -> Sp packed [kb][n(pad 2048)][kk]
// Each thread owns 8 consecutive cols (250 active threads); logits in regs.
// Pad cols 2000..2015 written as zeros (threads 250,251).
// ---------------------------------------------------------------------------
__global__ __launch_bounds__(256) void adj_softmax_pack(
    const float* __restrict__ nv1, const float* __restrict__ nv2,
    bf16* __restrict__ Sp)
{
    const int row = blockIdx.x;
    const int tid = threadIdx.x;
    const int j0  = tid * 8;
    __shared__ float sa[EMB];
    __shared__ float wred[4];
    __shared__ float bcast;
    if (tid < EMB) sa[tid] = nv1[row * EMB + tid];
    __syncthreads();

    const bool active = (tid < 250);
    float v[8] = {0,0,0,0,0,0,0,0};
    if (active) {
#pragma unroll
        for (int d = 0; d < EMB; ++d) {
            const float sd = sa[d];
            const float4 q0 = *(const float4*)&nv2[d * N_NODES + j0];
            const float4 q1 = *(const float4*)&nv2[d * N_NODES + j0 + 4];
            v[0] += sd * q0.x; v[1] += sd * q0.y; v[2] += sd * q0.z; v[3] += sd * q0.w;
            v[4] += sd * q1.x; v[5] += sd * q1.y; v[6] += sd * q1.z; v[7] += sd * q1.w;
        }
    }
    float lmax = 0.0f;   // relu floor
#pragma unroll
    for (int jj = 0; jj < 8; ++jj) { v[jj] = fmaxf(v[jj], 0.0f); lmax = fmaxf(lmax, v[jj]); }
#pragma unroll
    for (int off = 32; off > 0; off >>= 1)
        lmax = fmaxf(lmax, __shfl_down(lmax, off, 64));
    if ((tid & 63) == 0) wred[tid >> 6] = lmax;
    __syncthreads();
    if (tid == 0) bcast = fmaxf(fmaxf(wred[0], wred[1]), fmaxf(wred[2], wred[3]));
    __syncthreads();
    const float rmax = bcast;

    float lsum = 0.0f;
    if (active) {
#pragma unroll
        for (int jj = 0; jj < 8; ++jj) { v[jj] = __expf(v[jj] - rmax); lsum += v[jj]; }
    }
#pragma unroll
    for (int off = 32; off > 0; off >>= 1)
        lsum += __shfl_down(lsum, off, 64);
    if ((tid & 63) == 0) wred[tid >> 6] = lsum;
    __syncthreads();
    if (tid == 0) bcast = wred[0] + wred[1] + wred[2] + wred[3];
    __syncthreads();
    const float inv = 1.0f / bcast;

    if (tid < 252) {   // 250,251 write the zero pad (k 2000..2015)
        bf16x8 pk;
#pragma unroll
        for (int jj = 0; jj < 8; ++jj)
            pk[jj] = (bf16)(active ? v[jj] * inv : 0.0f);
        const int kb = j0 >> 5, kk = j0 & 31;
        *(bf16x8*)&Sp[((size_t)kb * NP + row) * 32 + kk] = pk;
    }
}

// ---------------------------------------------------------------------------
// Kernel 2: x [b][m][c] fp32 -> xTp packed [b][kb][c][kk] bf16 (k=m)
//           and xbf row-major [b][m][c] bf16.
// ---------------------------------------------------------------------------
__global__ __launch_bounds__(256) void transpose_pack_x(
    const float* __restrict__ X, bf16* __restrict__ Xtp, bf16* __restrict__ Xbf)
{
    const int b  = blockIdx.y;
    const int m0 = blockIdx.x * 64;
    const int tid = threadIdx.x;
    __shared__ bf16 T[64][72];   // [c][m]
#pragma unroll
    for (int i = 0; i < 4; ++i) {
        int idx = i * 256 + tid;
        int r  = idx >> 4;             // m offset
        int c4 = (idx & 15) * 4;
        int m  = m0 + r;
        float4 v = make_float4(0.f, 0.f, 0.f, 0.f);
        if (m < N_NODES)
            v = *(const float4*)&X[((size_t)b * N_NODES + m) * DIM + c4];
        bf16x4pk pk;
        pk.v[0] = (bf16)v.x; pk.v[1] = (bf16)v.y;
        pk.v[2] = (bf16)v.z; pk.v[3] = (bf16)v.w;
        if (m < N_NODES)
            *(bf16x4pk*)&Xbf[((size_t)b * N_NODES + m) * DIM + c4] = pk;
        T[c4 + 0][r] = pk.v[0];
        T[c4 + 1][r] = pk.v[1];
        T[c4 + 2][r] = pk.v[2];
        T[c4 + 3][r] = pk.v[3];
    }
    __syncthreads();
#pragma unroll
    for (int i = 0; i < 2; ++i) {
        int idx = i * 256 + tid;       // 0..511
        int c   = idx >> 3;
        int mch = idx & 7;             // 8-elem m-chunk
        int kb  = (m0 >> 5) + (mch >> 2);
        if (kb < KB) {
            int kk = (mch & 3) * 8;
            bf16x8 vv = *(const bf16x8*)&T[c][mch * 8];
            *(bf16x8*)&Xtp[((size_t)(b * KB + kb) * DIM + c) * 32 + kk] = vv;
        }
    }
}

// ---------------------------------------------------------------------------
// Kernel 3: Y[b,n,c] = sum_m S[n,m]*X[b,m,c], LDS-FREE fragment-direct MFMA.
// A = Sp [kb][n][kk], B = Btp [b][kb][c][kk]; every fragment load is one
// coalesced 1 KB global_load_dwordx4 per wave from L2. No barriers.
// Block: 128 n x 64 c (one batch); 4 waves 2x2, wave = 64n x 32c (4x2 MFMAs).
// Manual ping-pong prefetch across kb.
// ---------------------------------------------------------------------------
__global__ __launch_bounds__(256) void spmm_pack(
    const bf16* __restrict__ Ap, const bf16* __restrict__ Btp,
    bf16* __restrict__ Ybf, bf16* __restrict__ Ytp, int write_ytp)
{
    const int b   = blockIdx.x;
    const int n0  = blockIdx.y * 128;
    const int tid = threadIdx.x;
    const int lane = tid & 63, wave = tid >> 6;
    const int wm = wave >> 1, wn = wave & 1;
    const int l15 = lane & 15, quad = lane >> 4;

    const bf16* ab = Ap + ((size_t)(n0 + wm * 64 + l15)) * 32 + quad * 8;
    const bf16* bb = Btp + ((size_t)(b * KB) * DIM + wn * 32 + l15) * 32 + quad * 8;

    f32x4 acc[4][2] = {};
    bf16x8 afA[4], bfA[2], afB[4], bfB[2];

#define LOAD_A(dst, kb_) {                                               \
        const bf16* p = ab + (size_t)(kb_) * (NP * 32);                  \
        dst[0] = *(const bf16x8*)(p);                                    \
        dst[1] = *(const bf16x8*)(p + 16 * 32);                          \
        dst[2] = *(const bf16x8*)(p + 32 * 32);                          \
        dst[3] = *(const bf16x8*)(p + 48 * 32); }
#define LOAD_B(dst, kb_) {                                               \
        const bf16* p = bb + (size_t)(kb_) * (DIM * 32);                 \
        dst[0] = *(const bf16x8*)(p);                                    \
        dst[1] = *(const bf16x8*)(p + 16 * 32); }
#define MFMA8(af, bf) {                                                  \
        _Pragma("unroll")                                                \
        for (int rt = 0; rt < 4; ++rt) {                                 \
            acc[rt][0] = __builtin_amdgcn_mfma_f32_16x16x32_bf16(af[rt], bf[0], acc[rt][0], 0, 0, 0); \
            acc[rt][1] = __builtin_amdgcn_mfma_f32_16x16x32_bf16(af[rt], bf[1], acc[rt][1], 0, 0, 0); } }

    LOAD_A(afA, 0); LOAD_B(bfA, 0);
    for (int kb = 0; kb < 62; kb += 2) {
        LOAD_A(afB, kb + 1); LOAD_B(bfB, kb + 1);
        MFMA8(afA, bfA);
        if (kb + 2 < KB) { LOAD_A(afA, kb + 2); LOAD_B(bfA, kb + 2); }
        MFMA8(afB, bfB);
    }
    MFMA8(afA, bfA);   // kb = 62

    // Epilogue: C/D layout col = lane&15, row = quad*4 + reg
#pragma unroll
    for (int rt = 0; rt < 4; ++rt) {
        const int nbase = n0 + wm * 64 + rt * 16 + quad * 4;
#pragma unroll
        for (int ct = 0; ct < 2; ++ct) {
            const int c = wn * 32 + ct * 16 + l15;
#pragma unroll
            for (int r = 0; r < 4; ++r) {
                int n = nbase + r;
                if (n < N_NODES)
                    Ybf[((size_t)b * N_NODES + n) * DIM + c] = (bf16)acc[rt][ct][r];
            }
            if (write_ytp && nbase + 4 <= N_NODES) {
                bf16x4pk pk;
                pk.v[0] = (bf16)acc[rt][ct][0];
                pk.v[1] = (bf16)acc[rt][ct][1];
                pk.v[2] = (bf16)acc[rt][ct][2];
                pk.v[3] = (bf16)acc[rt][ct][3];
                const int kb2 = nbase >> 5, kk = nbase & 31;
                *(bf16x4pk*)&Ytp[((size_t)(b * KB + kb2) * DIM + c) * 32 + kk] = pk;
            }
        }
    }
#undef LOAD_A
#undef LOAD_B
#undef MFMA8
}

// ---------------------------------------------------------------------------
// Kernel 4a: wpT2[col][d] (d pad 32) + embp[n][d] (d pad 32), bf16
// ---------------------------------------------------------------------------
__global__ __launch_bounds__(256) void prep_small(
    const float* __restrict__ wp, const float* __restrict__ emb,
    bf16* __restrict__ wpT2, bf16* __restrict__ embp)
{
    int idx = blockIdx.x * 256 + threadIdx.x;
    if (idx < WCOLS * 32) {
        int col = idx >> 5, d = idx & 31;
        int o  = col / KI;
        int kk = col - o * KI;
        int cheb = kk >> 6, i = kk & 63;
        float v = (d < EMB) ? wp[(((d * 3 + cheb) * 64 + i) * 64) + o] : 0.0f;
        wpT2[idx] = (bf16)v;
    } else {
        int j = idx - WCOLS * 32;
        int n = j >> 5, d = j & 31;
        float v = (d < EMB) ? emb[n * EMB + d] : 0.0f;
        embp[j] = (bf16)v;
    }
}

// ---------------------------------------------------------------------------
// Kernel 4b: W[n][col] = sum_d embp[n][d] * wpT2[col][d]  (bf16 out)
// ---------------------------------------------------------------------------
__global__ __launch_bounds__(256) void prep_W_mfma(
    const bf16* __restrict__ embp, const bf16* __restrict__ wpT2,
    bf16* __restrict__ W)
{
    const int colbase = blockIdx.x * 256;
    const int n0      = blockIdx.y * 16;
    const int tid  = threadIdx.x;
    const int lane = tid & 63, wave = tid >> 6;
    const int l15 = lane & 15, quad = lane >> 4;

    __shared__ bf16 Cs[16][264];

    const bf16x8 af = *(const bf16x8*)&embp[(n0 + l15) * 32 + quad * 8];
    const f32x4 zero = {};
#pragma unroll
    for (int ct = 0; ct < 4; ++ct) {
        const int col = colbase + wave * 64 + ct * 16 + l15;
        bf16x8 bfr = *(const bf16x8*)&wpT2[(size_t)col * 32 + quad * 8];
        f32x4 acc = __builtin_amdgcn_mfma_f32_16x16x32_bf16(af, bfr, zero, 0, 0, 0);
#pragma unroll
        for (int r = 0; r < 4; ++r)
            Cs[quad * 4 + r][wave * 64 + ct * 16 + l15] = (bf16)acc[r];
    }
    __syncthreads();
    {
        const int row = tid >> 4;
        const int c16 = (tid & 15) * 16;
        bf16x8 v0 = *(const bf16x8*)&Cs[row][c16];
        bf16x8 v1 = *(const bf16x8*)&Cs[row][c16 + 8];
        bf16* dst = &W[(size_t)(n0 + row) * WCOLS + colbase + c16];
        *(bf16x8*)dst       = v0;
        *(bf16x8*)(dst + 8) = v1;
    }
}

// ---------------------------------------------------------------------------
// Kernel 5: per-node combine (bf16 inputs).
//   out[b,n,o] = sum_k xg[b,n,k] * W[n][o*192+k] + bias[n,o]
// ---------------------------------------------------------------------------
__global__ __launch_bounds__(256) void combine_node(
    const bf16* __restrict__ xbf, const bf16* __restrict__ y1bf,
    const bf16* __restrict__ y2bf, const float* __restrict__ emb,
    const float* __restrict__ bp, const bf16* __restrict__ W,
    float* __restrict__ out)
{
    const int n   = blockIdx.x;
    const int tid = threadIdx.x;
    const int lane = tid & 63, wave = tid >> 6;
    const int l15 = lane & 15, quad = lane >> 4;

    __shared__ bf16 As[BATCH][200];
    __shared__ bf16 Ws[DIM][200];
    __shared__ float bias_s[DIM];
    __shared__ float emb_s[EMB];

    if (tid < EMB) emb_s[tid] = emb[n * EMB + tid];

    {
        const int b  = tid >> 3;
        const int c8 = (tid & 7) * 8;
        const size_t base = ((size_t)b * N_NODES + n) * DIM + c8;
        bf16x8 vx = *(const bf16x8*)&xbf [base];
        bf16x8 v1 = *(const bf16x8*)&y1bf[base];
        bf16x8 v2 = *(const bf16x8*)&y2bf[base];
        bf16x8 p2;
#pragma unroll
        for (int e = 0; e < 8; ++e)
            p2[e] = (bf16)(2.0f * (float)v2[e] - (float)vx[e]);
        *(bf16x8*)&As[b][c8]       = vx;
        *(bf16x8*)&As[b][64 + c8]  = v1;
        *(bf16x8*)&As[b][128 + c8] = p2;
    }
    {
        const bf16* Wn = W + (size_t)n * WCOLS;
#pragma unroll
        for (int jj = 0; jj < 6; ++jj) {
            int chunk = jj * 256 + tid;
            int o  = chunk / 24;
            int kc = chunk - o * 24;
            bf16x8 v = *(const bf16x8*)&Wn[(size_t)chunk * 8];
            *(bf16x8*)&Ws[o][kc * 8] = v;
        }
    }
    __syncthreads();

    if (tid < DIM) {
        float s = 0.0f;
#pragma unroll
        for (int d = 0; d < EMB; ++d) s += emb_s[d] * bp[d * DIM + tid];
        bias_s[tid] = s;
    }

    bf16x8 af[2][6];
#pragma unroll
    for (int mt = 0; mt < 2; ++mt)
#pragma unroll
        for (int ks = 0; ks < 6; ++ks)
            af[mt][ks] = *(const bf16x8*)&As[mt * 16 + l15][ks * 32 + quad * 8];

    f32x4 acc[2] = {};
#pragma unroll
    for (int ks = 0; ks < 6; ++ks) {
        bf16x8 bfr = *(const bf16x8*)&Ws[wave * 16 + l15][ks * 32 + quad * 8];
        acc[0] = __builtin_amdgcn_mfma_f32_16x16x32_bf16(af[0][ks], bfr, acc[0], 0, 0, 0);
        acc[1] = __builtin_amdgcn_mfma_f32_16x16x32_bf16(af[1][ks], bfr, acc[1], 0, 0, 0);
    }
    __syncthreads();

    const int o = wave * 16 + l15;
    const float bv = bias_s[o];
#pragma unroll
    for (int mt = 0; mt < 2; ++mt)
#pragma unroll
        for (int r = 0; r < 4; ++r) {
            int b = mt * 16 + quad * 4 + r;
            out[((size_t)b * N_NODES + n) * DIM + o] = acc[mt][r] + bv;
        }
}

// ---------------------------------------------------------------------------
extern "C" void kernel_launch(void* const* d_in, const int* in_sizes, int n_in,
                              void* d_out, int out_size, void* d_ws, size_t ws_size,
                              hipStream_t stream) {
    const float* x   = (const float*)d_in[0];  // [32,2000,64]
    const float* emb = (const float*)d_in[1];  // [2000,16]
    const float* nv1 = (const float*)d_in[2];  // [2000,16]
    const float* nv2 = (const float*)d_in[3];  // [16,2000]
    const float* wp  = (const float*)d_in[4];  // [16,3,64,64]
    const float* bp  = (const float*)d_in[5];  // [16,64]
    float* out = (float*)d_out;                // [32,2000,64]

    char* w = (char*)d_ws;
    bf16* Sp   = (bf16*)w;  w += (size_t)KB * NP * 32 * 2;            //  8.26 MB
    bf16* xTp  = (bf16*)w;  w += (size_t)BATCH * KB * DIM * 32 * 2;   //  8.26 MB
    bf16* y1Tp = (bf16*)w;  w += (size_t)BATCH * KB * DIM * 32 * 2;   //  8.26 MB
    bf16* xbf  = (bf16*)w;  w += (size_t)BATCH * N_NODES * DIM * 2;   //  8.19 MB
    bf16* y1bf = (bf16*)w;  w += (size_t)BATCH * N_NODES * DIM * 2;   //  8.19 MB
    bf16* y2bf = (bf16*)w;  w += (size_t)BATCH * N_NODES * DIM * 2;   //  8.19 MB
    bf16* wpT2 = (bf16*)w;  w += (size_t)WCOLS * 32 * 2;              //  0.79 MB
    bf16* embp = (bf16*)w;  w += (size_t)N_NODES * 32 * 2;            //  0.13 MB
    bf16* W    = (bf16*)w;                                            // 49.15 MB

    adj_softmax_pack<<<N_NODES, 256, 0, stream>>>(nv1, nv2, Sp);
    transpose_pack_x<<<dim3(32, BATCH), 256, 0, stream>>>(x, xTp, xbf);
    prep_small<<<(WCOLS * 32 + N_NODES * 32) / 256, 256, 0, stream>>>(wp, emb, wpT2, embp);
    prep_W_mfma<<<dim3(WCOLS / 256, N_NODES / 16), 256, 0, stream>>>(embp, wpT2, W);
    spmm_pack<<<dim3(BATCH, 16), 256, 0, stream>>>(Sp, xTp,  y1bf, y1Tp, 1);
    spmm_pack<<<dim3(BATCH, 16), 256, 0, stream>>>(Sp, y1Tp, y2bf, y1Tp, 0);
    combine_node<<<N_NODES, 256, 0, stream>>>(xbf, y1bf, y2bf, emb, bp, W, out);
}

// Round 6
// 220.353 us; speedup vs baseline: 1.0047x; 1.0047x over previous
//
#include <hip/hip_runtime.h>

#define N_NODES 2000
#define NP      2048    // Sp n-dim padding
#define KB      63      // ceil(2000/32) k-blocks (k padded to 2016 with zeros)
#define BATCH   32
#define DIM     64      // DIM_IN == DIM_OUT
#define EMB     16
#define KI      192     // CHEB_K * DIM_IN
#define WCOLS   12288   // DIM_OUT * KI

typedef __bf16 bf16;
typedef __attribute__((ext_vector_type(8))) __bf16 bf16x8;
typedef __attribute__((ext_vector_type(4))) float  f32x4;

struct alignas(8) bf16x4pk { bf16 v[4]; };

// ---------------------------------------------------------------------------
// Kernel 1: softmax(relu(nv1@nv2)) row -> Sp packed [kb][n(pad 2048)][kk]
// ---------------------------------------------------------------------------
__global__ __launch_bounds__(256) void adj_softmax_pack(
    const float* __restrict__ nv1, const float* __restrict__ nv2,
    bf16* __restrict__ Sp)
{
    const int row = blockIdx.x;
    const int tid = threadIdx.x;
    const int j0  = tid * 8;
    __shared__ float sa[EMB];
    __shared__ float wred[4];
    __shared__ float bcast;
    if (tid < EMB) sa[tid] = nv1[row * EMB + tid];
    __syncthreads();

    const bool active = (tid < 250);
    float v[8] = {0,0,0,0,0,0,0,0};
    if (active) {
#pragma unroll
        for (int d = 0; d < EMB; ++d) {
            const float sd = sa[d];
            const float4 q0 = *(const float4*)&nv2[d * N_NODES + j0];
            const float4 q1 = *(const float4*)&nv2[d * N_NODES + j0 + 4];
            v[0] += sd * q0.x; v[1] += sd * q0.y; v[2] += sd * q0.z; v[3] += sd * q0.w;
            v[4] += sd * q1.x; v[5] += sd * q1.y; v[6] += sd * q1.z; v[7] += sd * q1.w;
        }
    }
    float lmax = 0.0f;
#pragma unroll
    for (int jj = 0; jj < 8; ++jj) { v[jj] = fmaxf(v[jj], 0.0f); lmax = fmaxf(lmax, v[jj]); }
#pragma unroll
    for (int off = 32; off > 0; off >>= 1)
        lmax = fmaxf(lmax, __shfl_down(lmax, off, 64));
    if ((tid & 63) == 0) wred[tid >> 6] = lmax;
    __syncthreads();
    if (tid == 0) bcast = fmaxf(fmaxf(wred[0], wred[1]), fmaxf(wred[2], wred[3]));
    __syncthreads();
    const float rmax = bcast;

    float lsum = 0.0f;
    if (active) {
#pragma unroll
        for (int jj = 0; jj < 8; ++jj) { v[jj] = __expf(v[jj] - rmax); lsum += v[jj]; }
    }
#pragma unroll
    for (int off = 32; off > 0; off >>= 1)
        lsum += __shfl_down(lsum, off, 64);
    if ((tid & 63) == 0) wred[tid >> 6] = lsum;
    __syncthreads();
    if (tid == 0) bcast = wred[0] + wred[1] + wred[2] + wred[3];
    __syncthreads();
    const float inv = 1.0f / bcast;

    if (tid < 252) {
        bf16x8 pk;
#pragma unroll
        for (int jj = 0; jj < 8; ++jj)
            pk[jj] = (bf16)(active ? v[jj] * inv : 0.0f);
        const int kb = j0 >> 5, kk = j0 & 31;
        *(bf16x8*)&Sp[((size_t)kb * NP + row) * 32 + kk] = pk;
    }
}

// ---------------------------------------------------------------------------
// Kernel 2: x [b][m][c] fp32 -> xTp packed [b][kb][c][kk] bf16 + xbf row-major
// ---------------------------------------------------------------------------
__global__ __launch_bounds__(256) void transpose_pack_x(
    const float* __restrict__ X, bf16* __restrict__ Xtp, bf16* __restrict__ Xbf)
{
    const int b  = blockIdx.y;
    const int m0 = blockIdx.x * 64;
    const int tid = threadIdx.x;
    __shared__ bf16 T[64][72];
#pragma unroll
    for (int i = 0; i < 4; ++i) {
        int idx = i * 256 + tid;
        int r  = idx >> 4;
        int c4 = (idx & 15) * 4;
        int m  = m0 + r;
        float4 v = make_float4(0.f, 0.f, 0.f, 0.f);
        if (m < N_NODES)
            v = *(const float4*)&X[((size_t)b * N_NODES + m) * DIM + c4];
        bf16x4pk pk;
        pk.v[0] = (bf16)v.x; pk.v[1] = (bf16)v.y;
        pk.v[2] = (bf16)v.z; pk.v[3] = (bf16)v.w;
        if (m < N_NODES)
            *(bf16x4pk*)&Xbf[((size_t)b * N_NODES + m) * DIM + c4] = pk;
        T[c4 + 0][r] = pk.v[0];
        T[c4 + 1][r] = pk.v[1];
        T[c4 + 2][r] = pk.v[2];
        T[c4 + 3][r] = pk.v[3];
    }
    __syncthreads();
#pragma unroll
    for (int i = 0; i < 2; ++i) {
        int idx = i * 256 + tid;
        int c   = idx >> 3;
        int mch = idx & 7;
        int kb  = (m0 >> 5) + (mch >> 2);
        if (kb < KB) {
            int kk = (mch & 3) * 8;
            bf16x8 vv = *(const bf16x8*)&T[c][mch * 8];
            *(bf16x8*)&Xtp[((size_t)(b * KB + kb) * DIM + c) * 32 + kk] = vv;
        }
    }
}

// ---------------------------------------------------------------------------
// Kernel 3: LDS-free fragment-direct MFMA spmm with 3-deep rotating
// register pipeline (KB = 63 = 3*21). No barriers: compiler emits partial
// vmcnt waits; ~18 loads in flight covers L2 latency.
// Block: 128 n x 64 c (one batch); wave = 64n x 32c (4x2 MFMAs / kb).
// ---------------------------------------------------------------------------
__global__ __launch_bounds__(256) void spmm_pack(
    const bf16* __restrict__ Ap, const bf16* __restrict__ Btp,
    bf16* __restrict__ Ybf, bf16* __restrict__ Ytp, int write_ytp)
{
    const int b   = blockIdx.x;
    const int n0  = blockIdx.y * 128;
    const int tid = threadIdx.x;
    const int lane = tid & 63, wave = tid >> 6;
    const int wm = wave >> 1, wn = wave & 1;
    const int l15 = lane & 15, quad = lane >> 4;

    const bf16* ab = Ap + ((size_t)(n0 + wm * 64 + l15)) * 32 + quad * 8;
    const bf16* bb = Btp + ((size_t)(b * KB) * DIM + wn * 32 + l15) * 32 + quad * 8;

    f32x4 acc[4][2] = {};
    bf16x8 abuf[3][4], bbuf[3][2];

#define LOAD_ST(st, kb_) {                                               \
        const bf16* pa = ab + (size_t)(kb_) * (NP * 32);                 \
        abuf[st][0] = *(const bf16x8*)(pa);                              \
        abuf[st][1] = *(const bf16x8*)(pa + 16 * 32);                    \
        abuf[st][2] = *(const bf16x8*)(pa + 32 * 32);                    \
        abuf[st][3] = *(const bf16x8*)(pa + 48 * 32);                    \
        const bf16* pb = bb + (size_t)(kb_) * (DIM * 32);                \
        bbuf[st][0] = *(const bf16x8*)(pb);                              \
        bbuf[st][1] = *(const bf16x8*)(pb + 16 * 32); }
#define MFMA_ST(st) {                                                    \
        _Pragma("unroll")                                                \
        for (int rt = 0; rt < 4; ++rt) {                                 \
            acc[rt][0] = __builtin_amdgcn_mfma_f32_16x16x32_bf16(abuf[st][rt], bbuf[st][0], acc[rt][0], 0, 0, 0); \
            acc[rt][1] = __builtin_amdgcn_mfma_f32_16x16x32_bf16(abuf[st][rt], bbuf[st][1], acc[rt][1], 0, 0, 0); } }

    LOAD_ST(0, 0); LOAD_ST(1, 1); LOAD_ST(2, 2);
#pragma unroll 1
    for (int kb0 = 0; kb0 < KB; kb0 += 3) {
        const int k3 = (kb0 + 3 > 62) ? 62 : kb0 + 3;   // tail: redundant reload
        const int k4 = (kb0 + 4 > 62) ? 62 : kb0 + 4;
        const int k5 = (kb0 + 5 > 62) ? 62 : kb0 + 5;
        MFMA_ST(0); LOAD_ST(0, k3);
        MFMA_ST(1); LOAD_ST(1, k4);
        MFMA_ST(2); LOAD_ST(2, k5);
    }
#undef LOAD_ST
#undef MFMA_ST

    // Epilogue: C/D layout col = lane&15, row = quad*4 + reg
#pragma unroll
    for (int rt = 0; rt < 4; ++rt) {
        const int nbase = n0 + wm * 64 + rt * 16 + quad * 4;
#pragma unroll
        for (int ct = 0; ct < 2; ++ct) {
            const int c = wn * 32 + ct * 16 + l15;
#pragma unroll
            for (int r = 0; r < 4; ++r) {
                int n = nbase + r;
                if (n < N_NODES)
                    Ybf[((size_t)b * N_NODES + n) * DIM + c] = (bf16)acc[rt][ct][r];
            }
            if (write_ytp && nbase + 4 <= N_NODES) {
                bf16x4pk pk;
                pk.v[0] = (bf16)acc[rt][ct][0];
                pk.v[1] = (bf16)acc[rt][ct][1];
                pk.v[2] = (bf16)acc[rt][ct][2];
                pk.v[3] = (bf16)acc[rt][ct][3];
                const int kb2 = nbase >> 5, kk = nbase & 31;
                *(bf16x4pk*)&Ytp[((size_t)(b * KB + kb2) * DIM + c) * 32 + kk] = pk;
            }
        }
    }
}

// ---------------------------------------------------------------------------
// Kernel 4a: wpT2[col][d] (d pad 32) + embp[n][d] (d pad 32), bf16
// ---------------------------------------------------------------------------
__global__ __launch_bounds__(256) void prep_small(
    const float* __restrict__ wp, const float* __restrict__ emb,
    bf16* __restrict__ wpT2, bf16* __restrict__ embp)
{
    int idx = blockIdx.x * 256 + threadIdx.x;
    if (idx < WCOLS * 32) {
        int col = idx >> 5, d = idx & 31;
        int o  = col / KI;
        int kk = col - o * KI;
        int cheb = kk >> 6, i = kk & 63;
        float v = (d < EMB) ? wp[(((d * 3 + cheb) * 64 + i) * 64) + o] : 0.0f;
        wpT2[idx] = (bf16)v;
    } else {
        int j = idx - WCOLS * 32;
        int n = j >> 5, d = j & 31;
        float v = (d < EMB) ? emb[n * EMB + d] : 0.0f;
        embp[j] = (bf16)v;
    }
}

// ---------------------------------------------------------------------------
// Kernel 4b: W[n][col] = sum_d embp[n][d] * wpT2[col][d]  (bf16 out)
// ---------------------------------------------------------------------------
__global__ __launch_bounds__(256) void prep_W_mfma(
    const bf16* __restrict__ embp, const bf16* __restrict__ wpT2,
    bf16* __restrict__ W)
{
    const int colbase = blockIdx.x * 256;
    const int n0      = blockIdx.y * 16;
    const int tid  = threadIdx.x;
    const int lane = tid & 63, wave = tid >> 6;
    const int l15 = lane & 15, quad = lane >> 4;

    __shared__ bf16 Cs[16][264];

    const bf16x8 af = *(const bf16x8*)&embp[(n0 + l15) * 32 + quad * 8];
    const f32x4 zero = {};
#pragma unroll
    for (int ct = 0; ct < 4; ++ct) {
        const int col = colbase + wave * 64 + ct * 16 + l15;
        bf16x8 bfr = *(const bf16x8*)&wpT2[(size_t)col * 32 + quad * 8];
        f32x4 acc = __builtin_amdgcn_mfma_f32_16x16x32_bf16(af, bfr, zero, 0, 0, 0);
#pragma unroll
        for (int r = 0; r < 4; ++r)
            Cs[quad * 4 + r][wave * 64 + ct * 16 + l15] = (bf16)acc[r];
    }
    __syncthreads();
    {
        const int row = tid >> 4;
        const int c16 = (tid & 15) * 16;
        bf16x8 v0 = *(const bf16x8*)&Cs[row][c16];
        bf16x8 v1 = *(const bf16x8*)&Cs[row][c16 + 8];
        bf16* dst = &W[(size_t)(n0 + row) * WCOLS + colbase + c16];
        *(bf16x8*)dst       = v0;
        *(bf16x8*)(dst + 8) = v1;
    }
}

// ---------------------------------------------------------------------------
// Kernel 5: per-node combine (bf16 inputs).
// ---------------------------------------------------------------------------
__global__ __launch_bounds__(256) void combine_node(
    const bf16* __restrict__ xbf, const bf16* __restrict__ y1bf,
    const bf16* __restrict__ y2bf, const float* __restrict__ emb,
    const float* __restrict__ bp, const bf16* __restrict__ W,
    float* __restrict__ out)
{
    const int n   = blockIdx.x;
    const int tid = threadIdx.x;
    const int lane = tid & 63, wave = tid >> 6;
    const int l15 = lane & 15, quad = lane >> 4;

    __shared__ bf16 As[BATCH][200];
    __shared__ bf16 Ws[DIM][200];
    __shared__ float bias_s[DIM];
    __shared__ float emb_s[EMB];

    if (tid < EMB) emb_s[tid] = emb[n * EMB + tid];

    {
        const int b  = tid >> 3;
        const int c8 = (tid & 7) * 8;
        const size_t base = ((size_t)b * N_NODES + n) * DIM + c8;
        bf16x8 vx = *(const bf16x8*)&xbf [base];
        bf16x8 v1 = *(const bf16x8*)&y1bf[base];
        bf16x8 v2 = *(const bf16x8*)&y2bf[base];
        bf16x8 p2;
#pragma unroll
        for (int e = 0; e < 8; ++e)
            p2[e] = (bf16)(2.0f * (float)v2[e] - (float)vx[e]);
        *(bf16x8*)&As[b][c8]       = vx;
        *(bf16x8*)&As[b][64 + c8]  = v1;
        *(bf16x8*)&As[b][128 + c8] = p2;
    }
    {
        const bf16* Wn = W + (size_t)n * WCOLS;
#pragma unroll
        for (int jj = 0; jj < 6; ++jj) {
            int chunk = jj * 256 + tid;
            int o  = chunk / 24;
            int kc = chunk - o * 24;
            bf16x8 v = *(const bf16x8*)&Wn[(size_t)chunk * 8];
            *(bf16x8*)&Ws[o][kc * 8] = v;
        }
    }
    __syncthreads();

    if (tid < DIM) {
        float s = 0.0f;
#pragma unroll
        for (int d = 0; d < EMB; ++d) s += emb_s[d] * bp[d * DIM + tid];
        bias_s[tid] = s;
    }

    bf16x8 af[2][6];
#pragma unroll
    for (int mt = 0; mt < 2; ++mt)
#pragma unroll
        for (int ks = 0; ks < 6; ++ks)
            af[mt][ks] = *(const bf16x8*)&As[mt * 16 + l15][ks * 32 + quad * 8];

    f32x4 acc[2] = {};
#pragma unroll
    for (int ks = 0; ks < 6; ++ks) {
        bf16x8 bfr = *(const bf16x8*)&Ws[wave * 16 + l15][ks * 32 + quad * 8];
        acc[0] = __builtin_amdgcn_mfma_f32_16x16x32_bf16(af[0][ks], bfr, acc[0], 0, 0, 0);
        acc[1] = __builtin_amdgcn_mfma_f32_16x16x32_bf16(af[1][ks], bfr, acc[1], 0, 0, 0);
    }
    __syncthreads();

    const int o = wave * 16 + l15;
    const float bv = bias_s[o];
#pragma unroll
    for (int mt = 0; mt < 2; ++mt)
#pragma unroll
        for (int r = 0; r < 4; ++r) {
            int b = mt * 16 + quad * 4 + r;
            out[((size_t)b * N_NODES + n) * DIM + o] = acc[mt][r] + bv;
        }
}

// ---------------------------------------------------------------------------
extern "C" void kernel_launch(void* const* d_in, const int* in_sizes, int n_in,
                              void* d_out, int out_size, void* d_ws, size_t ws_size,
                              hipStream_t stream) {
    const float* x   = (const float*)d_in[0];  // [32,2000,64]
    const float* emb = (const float*)d_in[1];  // [2000,16]
    const float* nv1 = (const float*)d_in[2];  // [2000,16]
    const float* nv2 = (const float*)d_in[3];  // [16,2000]
    const float* wp  = (const float*)d_in[4];  // [16,3,64,64]
    const float* bp  = (const float*)d_in[5];  // [16,64]
    float* out = (float*)d_out;                // [32,2000,64]

    char* w = (char*)d_ws;
    bf16* Sp   = (bf16*)w;  w += (size_t)KB * NP * 32 * 2;            //  8.26 MB
    bf16* xTp  = (bf16*)w;  w += (size_t)BATCH * KB * DIM * 32 * 2;   //  8.26 MB
    bf16* y1Tp = (bf16*)w;  w += (size_t)BATCH * KB * DIM * 32 * 2;   //  8.26 MB
    bf16* xbf  = (bf16*)w;  w += (size_t)BATCH * N_NODES * DIM * 2;   //  8.19 MB
    bf16* y1bf = (bf16*)w;  w += (size_t)BATCH * N_NODES * DIM * 2;   //  8.19 MB
    bf16* y2bf = (bf16*)w;  w += (size_t)BATCH * N_NODES * DIM * 2;   //  8.19 MB
    bf16* wpT2 = (bf16*)w;  w += (size_t)WCOLS * 32 * 2;              //  0.79 MB
    bf16* embp = (bf16*)w;  w += (size_t)N_NODES * 32 * 2;            //  0.13 MB
    bf16* W    = (bf16*)w;                                            // 49.15 MB

    adj_softmax_pack<<<N_NODES, 256, 0, stream>>>(nv1, nv2, Sp);
    transpose_pack_x<<<dim3(32, BATCH), 256, 0, stream>>>(x, xTp, xbf);
    prep_small<<<(WCOLS * 32 + N_NODES * 32) / 256, 256, 0, stream>>>(wp, emb, wpT2, embp);
    prep_W_mfma<<<dim3(WCOLS / 256, N_NODES / 16), 256, 0, stream>>>(embp, wpT2, W);
    spmm_pack<<<dim3(BATCH, 16), 256, 0, stream>>>(Sp, xTp,  y1bf, y1Tp, 1);
    spmm_pack<<<dim3(BATCH, 16), 256, 0, stream>>>(Sp, y1Tp, y2bf, y1Tp, 0);
    combine_node<<<N_NODES, 256, 0, stream>>>(xbf, y1bf, y2bf, emb, bp, W, out);
}